// Round 2
// baseline (1164.723 us; speedup 1.0000x reference)
//
#include <hip/hip_runtime.h>
#include <hip/hip_bf16.h>

// BERT stack: L=12(+1 dup of layer0), H=12, E=768, D=64, B=4, S=512 -> BS=2048 tokens.
// Faithful bugs preserved:
//  - attention flattens batch: 2048 tokens attend to each other globally, q==k==v
//  - zc = z.reshape(768,2048) is a FLAT VIEW of z[H][N][D]  (no transpose)
//  - mh = (wo@zc).reshape(B,S,E) is a FLAT VIEW of mh_mat[768][2048]
//  - pe: p = 10000 for e<384 else 10001; even e -> sin, odd -> cos; s = t % 512
// Inputs/outputs fp32. All GEMMs + attention bf16 MFMA (fp32 accumulate);
// residual/LN chain fp32. Weights pre-converted to bf16 once per launch.
// Attention: no-max softmax => additive partials, ksplit=2; S^T operand swap
// (qrow=lane&15) makes P->LDS 4xb64 and denominator a per-lane scalar.
// attn_combine is FUSED into gemm_out's B-staging (partial-sum + 1/l + f2bf);
// attn fp32 partials are L3-resident when gemm_out re-reads them.
// R1: all three GEMM kernels software-pipelined (global->reg prefetch of next
// K-tile issued between barrier and MFMA; grids are ~1.5 blocks/CU so TLP
// cannot hide latency, ILP must). s_setprio(1) around attn MFMA clusters.
// R2: f2bf uses native cast (compiler emits v_cvt_pk_bf16_f32 pairs; the old
// bit-twiddle blocked pattern-matching); softmax exp folded to single
// exp2f(s*0.125*log2e); ln_kernel rewritten wave-per-token (float4 loads,
// bf16x4 stores, shuffle-only reductions, no LDS/barriers).

#define BS_TOK 2048
#define EMB 768
#define NH 12
#define HD 64
#define WQN (12 * NH * EMB * HD)  // elems per weight stack (7077888)

typedef __attribute__((ext_vector_type(8))) short bf16x8;
typedef __attribute__((ext_vector_type(4))) short bf16x4;
typedef __attribute__((ext_vector_type(4))) float f32x4;

// Native RNE f32->bf16 (same rounding as previous bit-twiddle; lets the
// backend fuse pairs into v_cvt_pk_bf16_f32 on gfx950).
__device__ __forceinline__ short f2bf(float f) {
  union { __hip_bfloat16 h; short s; } u;
  u.h = __float2bfloat16(f);
  return u.s;
}

#define MFMA16(a, b, c) __builtin_amdgcn_mfma_f32_16x16x32_bf16(a, b, c, 0, 0, 0)
// XOR-swizzled LDS address for [r][k] tiles, 64-elem rows (zero-conflict, validated r3-r8)
#define SW64(r, k) ((r) * 64 + ((((k) >> 3) ^ ((r) & 7)) << 3) + ((k) & 7))

// ---------------------------------------------------------------- weight prep
__global__ __launch_bounds__(256) void cvt_weights_kernel(const float* __restrict__ wo,
                                                          const float* __restrict__ fw,
                                                          short* __restrict__ wob,
                                                          short* __restrict__ fwb) {
  const float* src = blockIdx.y ? fw : wo;
  short* dst = blockIdx.y ? fwb : wob;
  int i = (blockIdx.x * 256 + threadIdx.x) * 8;
  float4 a = *(const float4*)(src + i);
  float4 b = *(const float4*)(src + i + 4);
  bf16x8 t;
  t[0] = f2bf(a.x); t[1] = f2bf(a.y); t[2] = f2bf(a.z); t[3] = f2bf(a.w);
  t[4] = f2bf(b.x); t[5] = f2bf(b.y); t[6] = f2bf(b.z); t[7] = f2bf(b.w);
  *(bf16x8*)(dst + i) = t;
}

// wqT[l][h][d][e] <- wq[l][h][e][d], bf16
__global__ __launch_bounds__(256) void wq_trans_kernel(const float* __restrict__ wq,
                                                       short* __restrict__ wqT) {
  __shared__ short T[64 * 64];
  const int et = blockIdx.x;  // e-tile (12)
  const int lh = blockIdx.y;  // l*NH+h (144)
  const int tid = threadIdx.x;
  const float* src = wq + ((size_t)lh * EMB + et * 64) * HD;
  {
    int r = tid >> 2, c16 = (tid & 3) << 4;
    const float* p = src + r * HD + c16;
    float4 x0 = *(const float4*)(p + 0);
    float4 x1 = *(const float4*)(p + 4);
    float4 x2 = *(const float4*)(p + 8);
    float4 x3 = *(const float4*)(p + 12);
    bf16x8 a, b;
    a[0] = f2bf(x0.x); a[1] = f2bf(x0.y); a[2] = f2bf(x0.z); a[3] = f2bf(x0.w);
    a[4] = f2bf(x1.x); a[5] = f2bf(x1.y); a[6] = f2bf(x1.z); a[7] = f2bf(x1.w);
    b[0] = f2bf(x2.x); b[1] = f2bf(x2.y); b[2] = f2bf(x2.z); b[3] = f2bf(x2.w);
    b[4] = f2bf(x3.x); b[5] = f2bf(x3.y); b[6] = f2bf(x3.z); b[7] = f2bf(x3.w);
    int g = c16 >> 3;
    *(bf16x8*)&T[r * 64 + ((g ^ (r & 7)) << 3)] = a;
    *(bf16x8*)&T[r * 64 + (((g + 1) ^ (r & 7)) << 3)] = b;
  }
  __syncthreads();
  {
    int d = tid >> 2, e16 = (tid & 3) << 4;
    bf16x8 t0, t1;
#pragma unroll
    for (int j = 0; j < 8; ++j) t0[j] = T[SW64(e16 + j, d)];
#pragma unroll
    for (int j = 0; j < 8; ++j) t1[j] = T[SW64(e16 + 8 + j, d)];
    short* q = wqT + ((size_t)lh * HD + d) * EMB + et * 64 + e16;
    *(bf16x8*)(q) = t0;
    *(bf16x8*)(q + 8) = t1;
  }
}

// ---------------------------------------------------------------- pe + tokens
__global__ __launch_bounds__(256) void pe_add_kernel(const float* __restrict__ tok,
                                                     float* __restrict__ X,
                                                     short* __restrict__ Xb) {
  int idx = blockIdx.x * 256 + threadIdx.x;   // < 2048*768
  int e = idx % EMB;
  int t = idx / EMB;
  int s = t & 511;                            // t = b*512 + s
  float p = (e < 384) ? 10000.0f : 10001.0f;  // 10000 XOR ((2e)//768)
  float ang = (float)s / p;
  float pe = (e & 1) ? cosf(ang) : sinf(ang);
  float v = tok[idx] + pe;
  X[idx] = v;
  Xb[idx] = f2bf(v);
}

// ---------------- staging helpers (split load/write for reg-prefetch pipeline)
// 64 rows x 64 k, 256 threads: 2 x bf16x8 per thread
__device__ __forceinline__ void load64(const short* __restrict__ src, int ld,
                                       int row0, int k0, bf16x8* r, int tid) {
  int rr = tid >> 2, kb = (tid & 3) << 4;
  const short* p = src + (size_t)(row0 + rr) * ld + k0 + kb;
  r[0] = *(const bf16x8*)(p);
  r[1] = *(const bf16x8*)(p + 8);
}
__device__ __forceinline__ void write64(short* dst, const bf16x8* r, int tid) {
  int rr = tid >> 2, g = (tid & 3) << 1;
  *(bf16x8*)&dst[rr * 64 + (((g + 0) ^ (rr & 7)) << 3)] = r[0];
  *(bf16x8*)&dst[rr * 64 + (((g + 1) ^ (rr & 7)) << 3)] = r[1];
}

// 128 rows x 64 k, 256 threads: 4 x bf16x8 per thread
__device__ __forceinline__ void load128(const short* __restrict__ src, int ld,
                                        int row0, int k0, bf16x8* r, int tid) {
  int rr = tid >> 1, kb = (tid & 1) << 5;
  const short* p = src + (size_t)(row0 + rr) * ld + k0 + kb;
  r[0] = *(const bf16x8*)(p);
  r[1] = *(const bf16x8*)(p + 8);
  r[2] = *(const bf16x8*)(p + 16);
  r[3] = *(const bf16x8*)(p + 24);
}
__device__ __forceinline__ void write128(short* dst, const bf16x8* r, int tid) {
  int rr = tid >> 1, g = (tid & 1) << 2;
#pragma unroll
  for (int i = 0; i < 4; ++i)
    *(bf16x8*)&dst[rr * 64 + (((g + i) ^ (rr & 7)) << 3)] = r[i];
}

// fused combine+transpose staging for gemm_out:
// dst[n][k] <- bf16( (Op0+Op1)[(k0+k)*2048 + col0+n] / (Lp0+Lp1)[token] )
__device__ __forceinline__ void load_comb(const float* __restrict__ Op,
                                          const float* __restrict__ Lp,
                                          int k0, int col0, float4* a, float4* b,
                                          float& rl, int tid) {
  const int NB = BS_TOK * EMB;
  const int NHT = NH * BS_TOK;
  int kk = tid >> 2, nb = (tid & 3) << 4;
  size_t base = (size_t)(k0 + kk) * BS_TOK + col0 + nb;
  int hq = (int)(base >> 6);  // constant across the 16 cols (col0%64==0, nb+j<64)
  rl = 1.0f / (Lp[hq] + Lp[hq + NHT]);
#pragma unroll
  for (int q4 = 0; q4 < 4; ++q4) {
    a[q4] = *(const float4*)(Op + base + q4 * 4);
    b[q4] = *(const float4*)(Op + base + NB + q4 * 4);
  }
}
__device__ __forceinline__ void write_comb(short* dst, const float4* a,
                                           const float4* b, float rl, int tid) {
  int kk = tid >> 2, nb = (tid & 3) << 4;
#pragma unroll
  for (int q4 = 0; q4 < 4; ++q4) {
    dst[SW64(nb + q4 * 4 + 0, kk)] = f2bf((a[q4].x + b[q4].x) * rl);
    dst[SW64(nb + q4 * 4 + 1, kk)] = f2bf((a[q4].y + b[q4].y) * rl);
    dst[SW64(nb + q4 * 4 + 2, kk)] = f2bf((a[q4].z + b[q4].z) * rl);
    dst[SW64(nb + q4 * 4 + 3, kk)] = f2bf((a[q4].w + b[q4].w) * rl);
  }
}

// wave computes 16 rows x 64 cols (64x64 block tile, 4 waves)
#define GEMM_TILE_COMPUTE(As, Bs, acc)                                              \
  {                                                                                 \
    _Pragma("unroll") for (int s = 0; s < 2; ++s) {                                 \
      int ra = (w << 4) + l15;                                                      \
      bf16x8 af = *(const bf16x8*)&As[ra * 64 + ((((s << 2) + quad) ^ (ra & 7)) << 3)]; \
      _Pragma("unroll") for (int nt = 0; nt < 4; ++nt) {                            \
        int rb = (nt << 4) + l15;                                                   \
        bf16x8 bf = *(const bf16x8*)&Bs[rb * 64 + ((((s << 2) + quad) ^ (rb & 7)) << 3)]; \
        acc[nt] = MFMA16(af, bf, acc[nt]);                                          \
      }                                                                             \
    }                                                                               \
  }

// wave computes 32 rows x 64 cols (128x64 block tile, 4 waves); B-frag reused 2x
#define GEMM_TILE_COMPUTE2(As, Bs, acc)                                             \
  {                                                                                 \
    _Pragma("unroll") for (int s = 0; s < 2; ++s) {                                 \
      bf16x8 af[2];                                                                 \
      _Pragma("unroll") for (int u = 0; u < 2; ++u) {                               \
        int ra = (w << 5) + (u << 4) + l15;                                         \
        af[u] = *(const bf16x8*)&As[ra * 64 + ((((s << 2) + quad) ^ (ra & 7)) << 3)]; \
      }                                                                             \
      _Pragma("unroll") for (int nt = 0; nt < 4; ++nt) {                            \
        int rb = (nt << 4) + l15;                                                   \
        bf16x8 bf = *(const bf16x8*)&Bs[rb * 64 + ((((s << 2) + quad) ^ (rb & 7)) << 3)]; \
        acc[0][nt] = MFMA16(af[0], bf, acc[0][nt]);                                 \
        acc[1][nt] = MFMA16(af[1], bf, acc[1][nt]);                                 \
      }                                                                             \
    }                                                                               \
  }

// ------------------------------------------------- Q = Xb[2048x768] * WqT -> bf16 Q + Qt
// Software-pipelined: next K-tile global loads issued between barrier and MFMA.
__global__ __launch_bounds__(256) void gemm_q_kernel(const short* __restrict__ Xb,
                                                     const short* __restrict__ WqT,
                                                     short* __restrict__ Qo,
                                                     short* __restrict__ Qt) {
  __shared__ short As[64 * 64];
  __shared__ short Bs[64 * 64];
  const int m0 = blockIdx.x * 64;  // token tile
  const int h = blockIdx.y;        // head (N-tile of 64 = HD)
  const int tid = threadIdx.x;
  const int w = tid >> 6, lane = tid & 63, l15 = lane & 15, quad = lane >> 4;
  const short* wqh = WqT + (size_t)h * (HD * EMB);  // [d][e]
  f32x4 acc[4] = {(f32x4){0, 0, 0, 0}, (f32x4){0, 0, 0, 0},
                  (f32x4){0, 0, 0, 0}, (f32x4){0, 0, 0, 0}};
  bf16x8 ar[2], br[2];
  load64(Xb, EMB, m0, 0, ar, tid);
  load64(wqh, EMB, 0, 0, br, tid);
  for (int k0 = 0; k0 < EMB; k0 += 64) {
    if (k0) __syncthreads();
    write64(As, ar, tid);
    write64(Bs, br, tid);  // Bs[d][k]
    __syncthreads();
    if (k0 + 64 < EMB) {
      load64(Xb, EMB, m0, k0 + 64, ar, tid);
      load64(wqh, EMB, 0, k0 + 64, br, tid);
    }
    GEMM_TILE_COMPUTE(As, Bs, acc);
  }
  __syncthreads();
  // stage result tile into As as [tok][d]
#pragma unroll
  for (int nt = 0; nt < 4; ++nt)
#pragma unroll
    for (int r = 0; r < 4; ++r)
      As[SW64((w << 4) + (quad << 2) + r, (nt << 4) + l15)] = f2bf(acc[nt][r]);
  __syncthreads();
  {  // Qo[h][tok][d], coalesced b128 stores
    int r2 = tid >> 2, kb = (tid & 3) << 4;
    int g = kb >> 3;
    bf16x8 q0v = *(const bf16x8*)&As[r2 * 64 + ((g ^ (r2 & 7)) << 3)];
    bf16x8 q1v = *(const bf16x8*)&As[r2 * 64 + (((g + 1) ^ (r2 & 7)) << 3)];
    short* qo = Qo + (size_t)h * (BS_TOK * HD) + (size_t)(m0 + r2) * HD + kb;
    *(bf16x8*)(qo) = q0v;
    *(bf16x8*)(qo + 8) = q1v;
  }
  {  // Qt[h][d][tok], coalesced b128 stores
    int d = tid >> 2, tok0 = (tid & 3) << 4;
    bf16x8 t0, t1;
#pragma unroll
    for (int j = 0; j < 8; ++j) t0[j] = As[SW64(tok0 + j, d)];
#pragma unroll
    for (int j = 0; j < 8; ++j) t1[j] = As[SW64(tok0 + 8 + j, d)];
    short* qt = Qt + (size_t)h * (HD * BS_TOK) + (size_t)d * BS_TOK + m0 + tok0;
    *(bf16x8*)(qt) = t0;
    *(bf16x8*)(qt + 8) = t1;
  }
}

// ------------------------------------------------- flash attention
// 256 thr (4 waves), Q-tile 64 (16 rows/wave), K-tile 64, ksplit=2.
// S^T operand swap: MFMA(kf, qf) -> lane holds qrow=l15, keys=ct*16+quad*4+r.
// P->LDS: 4 x b64; denominator: per-lane scalar + 2 end shuffles.
__global__ __launch_bounds__(256) void attn_mfma_kernel(const short* __restrict__ Q,
                                                        const short* __restrict__ Qt,
                                                        float* __restrict__ Opart,
                                                        float* __restrict__ Lpart) {
  __shared__ short Ks[64 * 64];      // K[key][d]
  __shared__ short Vt[64 * 64];      // V^T[d][key]
  __shared__ short Pw[4 * 16 * 64];  // per-wave P[qrow][key]
  const int h = blockIdx.y;
  const int q0 = blockIdx.x * 64;
  const int kt0 = blockIdx.z * 16;   // 16 K-tiles per split
  const int tid = threadIdx.x;
  const int lane = tid & 63;
  const int wv = tid >> 6;
  const int l15 = lane & 15;
  const int quad = lane >> 4;
  const short* Qh = Q + (size_t)h * (BS_TOK * HD);
  const short* Qth = Qt + (size_t)h * (HD * BS_TOK);
  short* myP = Pw + wv * 16 * 64;

  bf16x8 qf[2];
  {
    const short* qp = Qh + (size_t)(q0 + wv * 16 + l15) * HD + quad * 8;
    qf[0] = *(const bf16x8*)(qp);
    qf[1] = *(const bf16x8*)(qp + 32);
  }

  f32x4 o[4];
  float lpl = 0.f;  // denominator partial for qrow = l15
#pragma unroll
  for (int r = 0; r < 4; ++r) o[r] = (f32x4){0.f, 0.f, 0.f, 0.f};

  // 2+2 b128 chunks per thread per tile (512 chunks per 8KB tile, 256 thr)
  bf16x8 kreg[2], vreg[2];
#pragma unroll
  for (int i = 0; i < 2; ++i) {
    int c = i * 256 + tid;
    kreg[i] = *(const bf16x8*)(Qh + kt0 * 4096 + c * 8);
    vreg[i] = *(const bf16x8*)(Qth + (c >> 3) * BS_TOK + kt0 * 64 + (c & 7) * 8);
  }

  for (int kt = 0; kt < 16; ++kt) {
    __syncthreads();
#pragma unroll
    for (int i = 0; i < 2; ++i) {
      int c = i * 256 + tid, row = c >> 3, g = c & 7;
      *(bf16x8*)&Ks[row * 64 + ((g ^ (row & 7)) << 3)] = kreg[i];
      *(bf16x8*)&Vt[row * 64 + ((g ^ (row & 7)) << 3)] = vreg[i];
    }
    __syncthreads();
    if (kt < 15) {
      int gt = kt0 + kt + 1;
#pragma unroll
      for (int i = 0; i < 2; ++i) {
        int c = i * 256 + tid;
        kreg[i] = *(const bf16x8*)(Qh + gt * 4096 + c * 8);
        vreg[i] = *(const bf16x8*)(Qth + (c >> 3) * BS_TOK + gt * 64 + (c & 7) * 8);
      }
    }

    // S^T = K Q^T  (4 key-tiles of 16); lane: qrow=l15, key=ct*16+quad*4+r
    f32x4 s[4];
    __builtin_amdgcn_s_setprio(1);
#pragma unroll
    for (int ct = 0; ct < 4; ++ct) {
      f32x4 acc = (f32x4){0.f, 0.f, 0.f, 0.f};
#pragma unroll
      for (int ks = 0; ks < 2; ++ks) {
        int row = ct * 16 + l15;  // key row of Ks = A-operand
        int c = ks * 4 + quad;
        bf16x8 kf = *(const bf16x8*)(&Ks[row * 64 + ((c ^ (row & 7)) << 3)]);
        acc = MFMA16(kf, qf[ks], acc);
      }
      s[ct] = acc;
    }
    __builtin_amdgcn_s_setprio(0);

    // no-max softmax: p = exp(s/8) = exp2(s*0.125*log2e); b64 P writes
#pragma unroll
    for (int ct = 0; ct < 4; ++ct) {
      bf16x4 pv4;
#pragma unroll
      for (int r = 0; r < 4; ++r) {
        float p = exp2f(s[ct][r] * 0.18033688011112042f);
        lpl += p;
        pv4[r] = f2bf(p);
      }
      int g = 2 * ct + (quad >> 1);
      *(bf16x4*)&myP[l15 * 64 + ((g ^ (l15 & 7)) << 3) + ((quad & 1) << 2)] = pv4;
    }

    // O += P V  (wave-local myP; in-wave lgkmcnt ordering, no barrier)
    __builtin_amdgcn_s_setprio(1);
#pragma unroll
    for (int ks = 0; ks < 2; ++ks) {
      int c = ks * 4 + quad;
      bf16x8 pf = *(const bf16x8*)(&myP[l15 * 64 + ((c ^ (l15 & 7)) << 3)]);
#pragma unroll
      for (int dt = 0; dt < 4; ++dt) {
        int row = dt * 16 + l15;
        bf16x8 vf = *(const bf16x8*)(&Vt[row * 64 + ((c ^ (row & 7)) << 3)]);
        o[dt] = MFMA16(pf, vf, o[dt]);
      }
    }
    __builtin_amdgcn_s_setprio(0);
  }

  // reduce denominator across quads (qrow = l15 fixed per lane)
  lpl += __shfl_xor(lpl, 16, 64);
  lpl += __shfl_xor(lpl, 32, 64);

  const int NB = BS_TOK * EMB;
  float* Oh = Opart + (size_t)blockIdx.z * NB + (size_t)h * (BS_TOK * HD);
  float* Lh = Lpart + ((size_t)blockIdx.z * NH + h) * BS_TOK;
  if (quad == 0) Lh[q0 + wv * 16 + l15] = lpl;
#pragma unroll
  for (int r = 0; r < 4; ++r) {
    int qrow = q0 + wv * 16 + quad * 4 + r;
#pragma unroll
    for (int dt = 0; dt < 4; ++dt)
      Oh[(size_t)qrow * HD + dt * 16 + l15] = o[dt][r];
  }
}

// ------------------------------------------------- MH = Wo * combine(Opart)/l
// 128x64 tiles, ksplit=2; combine fused into B staging. Software-pipelined.
__global__ __launch_bounds__(256) void gemm_out_kernel(const short* __restrict__ Wob,
                                                       const float* __restrict__ Op,
                                                       const float* __restrict__ Lp,
                                                       float* __restrict__ Pp) {
  __shared__ short As[128 * 64];
  __shared__ short Bs[64 * 64];
  const int n0 = blockIdx.x * 64;   // j cols (2048 -> 32)
  const int m0 = blockIdx.y * 128;  // e rows (768 -> 6)
  const int kz = blockIdx.z * 384;  // K half
  const int tid = threadIdx.x;
  const int w = tid >> 6, lane = tid & 63, l15 = lane & 15, quad = lane >> 4;
  f32x4 acc[2][4] = {};
  bf16x8 ar[4];
  float4 ca[4], cb[4];
  float rl;
  load128(Wob, EMB, m0, kz, ar, tid);
  load_comb(Op, Lp, kz, n0, ca, cb, rl, tid);
  for (int k0 = 0; k0 < 384; k0 += 64) {
    if (k0) __syncthreads();
    write128(As, ar, tid);
    write_comb(Bs, ca, cb, rl, tid);  // Bs[n][k] <- Z[k][n]
    __syncthreads();
    if (k0 + 64 < 384) {
      load128(Wob, EMB, m0, kz + k0 + 64, ar, tid);
      load_comb(Op, Lp, kz + k0 + 64, n0, ca, cb, rl, tid);
    }
    GEMM_TILE_COMPUTE2(As, Bs, acc);
  }
  float* P = Pp + (size_t)blockIdx.z * (BS_TOK * EMB);
#pragma unroll
  for (int u = 0; u < 2; ++u)
#pragma unroll
    for (int nt = 0; nt < 4; ++nt)
#pragma unroll
      for (int r = 0; r < 4; ++r)
        P[(size_t)(m0 + (w << 5) + (u << 4) + (quad << 2) + r) * BS_TOK + n0 +
          (nt << 4) + l15] = acc[u][nt][r];
}

// ------------------------------------------------- FFN = L1b * fwb^T + fb, 128x64, ksplit=2
__global__ __launch_bounds__(256) void gemm_ffn_kernel(const short* __restrict__ L1b,
                                                       const short* __restrict__ Fwb,
                                                       const float* __restrict__ Fb,
                                                       float* __restrict__ Pp) {
  __shared__ short As[128 * 64];
  __shared__ short Bs[64 * 64];
  const int m0 = blockIdx.x * 128;  // token tile (16)
  const int n0 = blockIdx.y * 64;   // out-feature tile (12)
  const int kz = blockIdx.z * 384;  // K half
  const int tid = threadIdx.x;
  const int w = tid >> 6, lane = tid & 63, l15 = lane & 15, quad = lane >> 4;
  f32x4 acc[2][4] = {};
  bf16x8 ar[4], br[2];
  load128(L1b, EMB, m0, kz, ar, tid);
  load64(Fwb, EMB, n0, kz, br, tid);
  for (int k0 = 0; k0 < 384; k0 += 64) {
    if (k0) __syncthreads();
    write128(As, ar, tid);
    write64(Bs, br, tid);  // fw[o][k]
    __syncthreads();
    if (k0 + 64 < 384) {
      load128(L1b, EMB, m0, kz + k0 + 64, ar, tid);
      load64(Fwb, EMB, n0, kz + k0 + 64, br, tid);
    }
    GEMM_TILE_COMPUTE2(As, Bs, acc);
  }
  float* P = Pp + (size_t)blockIdx.z * (BS_TOK * EMB);
  const bool addb = (blockIdx.z == 0);
#pragma unroll
  for (int nt = 0; nt < 4; ++nt) {
    float bias = addb ? Fb[n0 + (nt << 4) + l15] : 0.0f;
#pragma unroll
    for (int u = 0; u < 2; ++u)
#pragma unroll
      for (int r = 0; r < 4; ++r)
        P[(size_t)(m0 + (w << 5) + (u << 4) + (quad << 2) + r) * EMB + n0 +
          (nt << 4) + l15] = acc[u][nt][r] + bias;
  }
}

// ------------------------------------------------- LN(Xa + P0 + P1) -> fp32 + bf16
// Wave-per-token: 4 tokens/block, lane holds 12 elems (3 x float4), shuffle-only
// reductions, no LDS, no barriers. float4 loads, float4 + bf16x4 stores.
__global__ __launch_bounds__(256) void ln_kernel(const float* __restrict__ Xa,
                                                 const float* __restrict__ P,
                                                 const float* __restrict__ g,
                                                 const float* __restrict__ bb,
                                                 float* __restrict__ Out,
                                                 short* __restrict__ Outb) {
  const int NB = BS_TOK * EMB;
  const int wv = threadIdx.x >> 6, lane = threadIdx.x & 63;
  const int t = blockIdx.x * 4 + wv;
  const float* xa = Xa + (size_t)t * EMB;
  const float* p0 = P + (size_t)t * EMB;
  const float* p1 = p0 + NB;
  float4 v[3];
  float s = 0.f;
#pragma unroll
  for (int i = 0; i < 3; ++i) {
    int e = lane * 4 + i * 256;
    float4 a = *(const float4*)(xa + e);
    float4 b = *(const float4*)(p0 + e);
    float4 c = *(const float4*)(p1 + e);
    v[i].x = a.x + b.x + c.x;
    v[i].y = a.y + b.y + c.y;
    v[i].z = a.z + b.z + c.z;
    v[i].w = a.w + b.w + c.w;
    s += v[i].x + v[i].y + v[i].z + v[i].w;
  }
#pragma unroll
  for (int o = 32; o > 0; o >>= 1) s += __shfl_xor(s, o, 64);
  float mu = s * (1.0f / EMB);
  float q = 0.f;
#pragma unroll
  for (int i = 0; i < 3; ++i) {
    float dx = v[i].x - mu, dy = v[i].y - mu, dz = v[i].z - mu, dw = v[i].w - mu;
    q += dx * dx + dy * dy + dz * dz + dw * dw;
  }
#pragma unroll
  for (int o = 32; o > 0; o >>= 1) q += __shfl_xor(q, o, 64);
  float var = q * (1.0f / EMB);
  float r = rsqrtf(var + 1e-5f);
#pragma unroll
  for (int i = 0; i < 3; ++i) {
    int e = lane * 4 + i * 256;
    float4 gg = *(const float4*)(g + e);
    float4 bv = *(const float4*)(bb + e);
    float4 res;
    res.x = (v[i].x - mu) * r * gg.x + bv.x;
    res.y = (v[i].y - mu) * r * gg.y + bv.y;
    res.z = (v[i].z - mu) * r * gg.z + bv.z;
    res.w = (v[i].w - mu) * r * gg.w + bv.w;
    *(float4*)(Out + (size_t)t * EMB + e) = res;
    bf16x4 ob;
    ob[0] = f2bf(res.x);
    ob[1] = f2bf(res.y);
    ob[2] = f2bf(res.z);
    ob[3] = f2bf(res.w);
    *(bf16x4*)(Outb + (size_t)t * EMB + e) = ob;
  }
}

extern "C" void kernel_launch(void* const* d_in, const int* in_sizes, int n_in,
                              void* d_out, int out_size, void* d_ws, size_t ws_size,
                              hipStream_t stream) {
  const float* tok = (const float*)d_in[0];
  const float* wq = (const float*)d_in[1];
  const float* wo = (const float*)d_in[2];
  const float* g1 = (const float*)d_in[3];
  const float* b1 = (const float*)d_in[4];
  const float* fw = (const float*)d_in[5];
  const float* fb = (const float*)d_in[6];
  const float* g2 = (const float*)d_in[7];
  const float* b2 = (const float*)d_in[8];
  const int NB = BS_TOK * EMB;  // 1572864 elems
  float* bufA = (float*)d_ws;        // X (residual, fp32)
  float* bufB = bufA + NB;           // gemm partial 0
  float* bufC = bufB + NB;           // gemm partial 1
  float* bufD = bufC + NB;           // L1 fp32
  float* bufE = bufD + NB;           // attn O partial 0
  float* bufF = bufE + NB;           // attn O partial 1 (contiguous after E)
  short* XbA = (short*)(bufF + NB);  // bf16 of current X
  short* L1b = XbA + NB;             // bf16 of L1
  short* Qbf = L1b + NB;             // Q bf16 [H][2048][64]
  short* Qtb = Qbf + NB;             // Qt bf16 [H][64][2048]
  short* wqTb = Qtb + NB;            // wqT bf16 [L][H][64][768]
  short* wob = wqTb + WQN;           // wo bf16 [L][768][768]
  short* fwb = wob + WQN;            // fw bf16 [L][768][768]
  float* Lpart = (float*)(fwb + WQN);  // [2][H][2048]

  cvt_weights_kernel<<<dim3(WQN / (256 * 8), 2), 256, 0, stream>>>(wo, fw, wob, fwb);
  wq_trans_kernel<<<dim3(12, 12 * NH), 256, 0, stream>>>(wq, wqTb);
  pe_add_kernel<<<NB / 256, 256, 0, stream>>>(tok, bufA, XbA);
  for (int it = 0; it < 13; ++it) {
    int l = (it == 0) ? 0 : it - 1;  // layer 0 applied twice (faithful)
    gemm_q_kernel<<<dim3(32, NH), 256, 0, stream>>>(
        XbA, wqTb + (size_t)l * (NH * HD * EMB), Qbf, Qtb);
    attn_mfma_kernel<<<dim3(32, NH, 2), 256, 0, stream>>>(Qbf, Qtb, bufE, Lpart);
    gemm_out_kernel<<<dim3(32, 6, 2), 256, 0, stream>>>(
        wob + (size_t)l * (EMB * EMB), bufE, Lpart, bufB);
    ln_kernel<<<BS_TOK / 4, 256, 0, stream>>>(bufA, bufB, g1 + l * EMB, b1 + l * EMB,
                                              bufD, L1b);
    gemm_ffn_kernel<<<dim3(16, 12, 2), 256, 0, stream>>>(
        L1b, fwb + (size_t)l * (EMB * EMB), fb + l * EMB, bufB);
    float* ln2_dst = (it == 12) ? (float*)d_out : bufA;
    ln_kernel<<<BS_TOK / 4, 256, 0, stream>>>(bufD, bufB, g2 + l * EMB, b2 + l * EMB,
                                              ln2_dst, XbA);
  }
}

// Round 3
// 1161.235 us; speedup vs baseline: 1.0030x; 1.0030x over previous
//
#include <hip/hip_runtime.h>
#include <hip/hip_bf16.h>

// BERT stack: L=12(+1 dup of layer0), H=12, E=768, D=64, B=4, S=512 -> BS=2048 tokens.
// Faithful bugs preserved:
//  - attention flattens batch: 2048 tokens attend to each other globally, q==k==v
//  - zc = z.reshape(768,2048) is a FLAT VIEW of z[H][N][D]  (no transpose)
//  - mh = (wo@zc).reshape(B,S,E) is a FLAT VIEW of mh_mat[768][2048]
//  - pe: p = 10000 for e<384 else 10001; even e -> sin, odd -> cos; s = t % 512
// Inputs/outputs fp32. All GEMMs + attention bf16 MFMA (fp32 accumulate);
// residual/LN chain fp32. Weights pre-converted to bf16 once per launch.
// R1: reg-prefetch pipeline in GEMMs. R2: native f2bf (cvt_pk), exp2 softmax,
// wave-per-token LN. R1+R2 measured NEUTRAL (1170->1164).
// R3 (the fix): __syncthreads() drains vmcnt(0) on gfx950, killing the R1
// prefetch at every barrier. Inner loops now use raw `s_waitcnt lgkmcnt(0);
// s_barrier` (LDS-only drain) so global reg-prefetch loads stay in flight
// across barriers (T3/T4 counted-vmcnt pattern). All MFMA kernels converted
// to LDS double-buffer with ONE barrier per K-step. Attention: Q-tile 128
// (2 subtiles/wave, K/V staging amortized 2x), ksplit=4 -> grid 768 = 3
// blocks/CU balanced; gemm_out combine sums 4 partials.

#define BS_TOK 2048
#define EMB 768
#define NH 12
#define HD 64
#define WQN (12 * NH * EMB * HD)  // elems per weight stack (7077888)

typedef __attribute__((ext_vector_type(8))) short bf16x8;
typedef __attribute__((ext_vector_type(4))) short bf16x4;
typedef __attribute__((ext_vector_type(4))) float f32x4;

// Native RNE f32->bf16 (backend fuses pairs into v_cvt_pk_bf16_f32).
__device__ __forceinline__ short f2bf(float f) {
  union { __hip_bfloat16 h; short s; } u;
  u.h = __float2bfloat16(f);
  return u.s;
}

#define MFMA16(a, b, c) __builtin_amdgcn_mfma_f32_16x16x32_bf16(a, b, c, 0, 0, 0)
// XOR-swizzled LDS address for [r][k] tiles, 64-elem rows (zero-conflict)
#define SW64(r, k) ((r) * 64 + ((((k) >> 3) ^ ((r) & 7)) << 3) + ((k) & 7))
// Barrier that drains LDS ops only — in-flight global loads cross it.
#define BAR() asm volatile("s_waitcnt lgkmcnt(0)\n\ts_barrier" ::: "memory")

// ---------------------------------------------------------------- weight prep
__global__ __launch_bounds__(256) void cvt_weights_kernel(const float* __restrict__ wo,
                                                          const float* __restrict__ fw,
                                                          short* __restrict__ wob,
                                                          short* __restrict__ fwb) {
  const float* src = blockIdx.y ? fw : wo;
  short* dst = blockIdx.y ? fwb : wob;
  int i = (blockIdx.x * 256 + threadIdx.x) * 8;
  float4 a = *(const float4*)(src + i);
  float4 b = *(const float4*)(src + i + 4);
  bf16x8 t;
  t[0] = f2bf(a.x); t[1] = f2bf(a.y); t[2] = f2bf(a.z); t[3] = f2bf(a.w);
  t[4] = f2bf(b.x); t[5] = f2bf(b.y); t[6] = f2bf(b.z); t[7] = f2bf(b.w);
  *(bf16x8*)(dst + i) = t;
}

// wqT[l][h][d][e] <- wq[l][h][e][d], bf16
__global__ __launch_bounds__(256) void wq_trans_kernel(const float* __restrict__ wq,
                                                       short* __restrict__ wqT) {
  __shared__ short T[64 * 64];
  const int et = blockIdx.x;  // e-tile (12)
  const int lh = blockIdx.y;  // l*NH+h (144)
  const int tid = threadIdx.x;
  const float* src = wq + ((size_t)lh * EMB + et * 64) * HD;
  {
    int r = tid >> 2, c16 = (tid & 3) << 4;
    const float* p = src + r * HD + c16;
    float4 x0 = *(const float4*)(p + 0);
    float4 x1 = *(const float4*)(p + 4);
    float4 x2 = *(const float4*)(p + 8);
    float4 x3 = *(const float4*)(p + 12);
    bf16x8 a, b;
    a[0] = f2bf(x0.x); a[1] = f2bf(x0.y); a[2] = f2bf(x0.z); a[3] = f2bf(x0.w);
    a[4] = f2bf(x1.x); a[5] = f2bf(x1.y); a[6] = f2bf(x1.z); a[7] = f2bf(x1.w);
    b[0] = f2bf(x2.x); b[1] = f2bf(x2.y); b[2] = f2bf(x2.z); b[3] = f2bf(x2.w);
    b[4] = f2bf(x3.x); b[5] = f2bf(x3.y); b[6] = f2bf(x3.z); b[7] = f2bf(x3.w);
    int g = c16 >> 3;
    *(bf16x8*)&T[r * 64 + ((g ^ (r & 7)) << 3)] = a;
    *(bf16x8*)&T[r * 64 + (((g + 1) ^ (r & 7)) << 3)] = b;
  }
  __syncthreads();
  {
    int d = tid >> 2, e16 = (tid & 3) << 4;
    bf16x8 t0, t1;
#pragma unroll
    for (int j = 0; j < 8; ++j) t0[j] = T[SW64(e16 + j, d)];
#pragma unroll
    for (int j = 0; j < 8; ++j) t1[j] = T[SW64(e16 + 8 + j, d)];
    short* q = wqT + ((size_t)lh * HD + d) * EMB + et * 64 + e16;
    *(bf16x8*)(q) = t0;
    *(bf16x8*)(q + 8) = t1;
  }
}

// ---------------------------------------------------------------- pe + tokens
__global__ __launch_bounds__(256) void pe_add_kernel(const float* __restrict__ tok,
                                                     float* __restrict__ X,
                                                     short* __restrict__ Xb) {
  int idx = blockIdx.x * 256 + threadIdx.x;   // < 2048*768
  int e = idx % EMB;
  int t = idx / EMB;
  int s = t & 511;                            // t = b*512 + s
  float p = (e < 384) ? 10000.0f : 10001.0f;  // 10000 XOR ((2e)//768)
  float ang = (float)s / p;
  float pe = (e & 1) ? cosf(ang) : sinf(ang);
  float v = tok[idx] + pe;
  X[idx] = v;
  Xb[idx] = f2bf(v);
}

// ---------------- staging helpers (split load/write for reg-prefetch pipeline)
// 64 rows x 64 k, 256 threads: 2 x bf16x8 per thread
__device__ __forceinline__ void load64(const short* __restrict__ src, int ld,
                                       int row0, int k0, bf16x8* r, int tid) {
  int rr = tid >> 2, kb = (tid & 3) << 4;
  const short* p = src + (size_t)(row0 + rr) * ld + k0 + kb;
  r[0] = *(const bf16x8*)(p);
  r[1] = *(const bf16x8*)(p + 8);
}
__device__ __forceinline__ void write64(short* dst, const bf16x8* r, int tid) {
  int rr = tid >> 2, g = (tid & 3) << 1;
  *(bf16x8*)&dst[rr * 64 + (((g + 0) ^ (rr & 7)) << 3)] = r[0];
  *(bf16x8*)&dst[rr * 64 + (((g + 1) ^ (rr & 7)) << 3)] = r[1];
}

// 128 rows x 64 k, 256 threads: 4 x bf16x8 per thread
__device__ __forceinline__ void load128(const short* __restrict__ src, int ld,
                                        int row0, int k0, bf16x8* r, int tid) {
  int rr = tid >> 1, kb = (tid & 1) << 5;
  const short* p = src + (size_t)(row0 + rr) * ld + k0 + kb;
  r[0] = *(const bf16x8*)(p);
  r[1] = *(const bf16x8*)(p + 8);
  r[2] = *(const bf16x8*)(p + 16);
  r[3] = *(const bf16x8*)(p + 24);
}
__device__ __forceinline__ void write128(short* dst, const bf16x8* r, int tid) {
  int rr = tid >> 1, g = (tid & 1) << 2;
#pragma unroll
  for (int i = 0; i < 4; ++i)
    *(bf16x8*)&dst[rr * 64 + (((g + i) ^ (rr & 7)) << 3)] = r[i];
}

// fused 4-way combine+transpose staging for gemm_out:
// dst[n][k] <- bf16( (sum_z Opz)[(k0+k)*2048 + col0+n] / (sum_z Lpz)[token] )
__device__ __forceinline__ void load_comb(const float* __restrict__ Op,
                                          const float* __restrict__ Lp,
                                          int k0, int col0, float4 a[4][4],
                                          float& rl, int tid) {
  const int NB = BS_TOK * EMB;
  const int NHT = NH * BS_TOK;
  int kk = tid >> 2, nb = (tid & 3) << 4;
  size_t base = (size_t)(k0 + kk) * BS_TOK + col0 + nb;
  int hq = (int)(base >> 6);  // constant across the 16 cols (col0%64==0, nb+j<64)
  rl = 1.0f / ((Lp[hq] + Lp[hq + NHT]) + (Lp[hq + 2 * NHT] + Lp[hq + 3 * NHT]));
#pragma unroll
  for (int z = 0; z < 4; ++z)
#pragma unroll
    for (int q4 = 0; q4 < 4; ++q4)
      a[z][q4] = *(const float4*)(Op + base + (size_t)z * NB + q4 * 4);
}
__device__ __forceinline__ void write_comb(short* dst, const float4 a[4][4],
                                           float rl, int tid) {
  int kk = tid >> 2, nb = (tid & 3) << 4;
#pragma unroll
  for (int q4 = 0; q4 < 4; ++q4) {
    dst[SW64(nb + q4 * 4 + 0, kk)] =
        f2bf(((a[0][q4].x + a[1][q4].x) + (a[2][q4].x + a[3][q4].x)) * rl);
    dst[SW64(nb + q4 * 4 + 1, kk)] =
        f2bf(((a[0][q4].y + a[1][q4].y) + (a[2][q4].y + a[3][q4].y)) * rl);
    dst[SW64(nb + q4 * 4 + 2, kk)] =
        f2bf(((a[0][q4].z + a[1][q4].z) + (a[2][q4].z + a[3][q4].z)) * rl);
    dst[SW64(nb + q4 * 4 + 3, kk)] =
        f2bf(((a[0][q4].w + a[1][q4].w) + (a[2][q4].w + a[3][q4].w)) * rl);
  }
}

// wave computes 16 rows x 64 cols (64x64 block tile, 4 waves)
#define GEMM_TILE_COMPUTE(As, Bs, acc)                                              \
  {                                                                                 \
    _Pragma("unroll") for (int s = 0; s < 2; ++s) {                                 \
      int ra = (w << 4) + l15;                                                      \
      bf16x8 af = *(const bf16x8*)&As[ra * 64 + ((((s << 2) + quad) ^ (ra & 7)) << 3)]; \
      _Pragma("unroll") for (int nt = 0; nt < 4; ++nt) {                            \
        int rb = (nt << 4) + l15;                                                   \
        bf16x8 bf = *(const bf16x8*)&Bs[rb * 64 + ((((s << 2) + quad) ^ (rb & 7)) << 3)]; \
        acc[nt] = MFMA16(af, bf, acc[nt]);                                          \
      }                                                                             \
    }                                                                               \
  }

// wave computes 32 rows x 64 cols (128x64 block tile, 4 waves); B-frag reused 2x
#define GEMM_TILE_COMPUTE2(As, Bs, acc)                                             \
  {                                                                                 \
    _Pragma("unroll") for (int s = 0; s < 2; ++s) {                                 \
      bf16x8 af[2];                                                                 \
      _Pragma("unroll") for (int u = 0; u < 2; ++u) {                               \
        int ra = (w << 5) + (u << 4) + l15;                                         \
        af[u] = *(const bf16x8*)&As[ra * 64 + ((((s << 2) + quad) ^ (ra & 7)) << 3)]; \
      }                                                                             \
      _Pragma("unroll") for (int nt = 0; nt < 4; ++nt) {                            \
        int rb = (nt << 4) + l15;                                                   \
        bf16x8 bf = *(const bf16x8*)&Bs[rb * 64 + ((((s << 2) + quad) ^ (rb & 7)) << 3)]; \
        acc[0][nt] = MFMA16(af[0], bf, acc[0][nt]);                                 \
        acc[1][nt] = MFMA16(af[1], bf, acc[1][nt]);                                 \
      }                                                                             \
    }                                                                               \
  }

// ------------------------------------------------- Q = Xb[2048x768] * WqT -> bf16 Q + Qt
// LDS double-buffered, one LDS-only barrier per K-step; global prefetch stays
// in flight across barriers.
__global__ __launch_bounds__(256) void gemm_q_kernel(const short* __restrict__ Xb,
                                                     const short* __restrict__ WqT,
                                                     short* __restrict__ Qo,
                                                     short* __restrict__ Qt) {
  __shared__ short As[2][64 * 64];
  __shared__ short Bs[2][64 * 64];
  const int m0 = blockIdx.x * 64;  // token tile
  const int h = blockIdx.y;        // head (N-tile of 64 = HD)
  const int tid = threadIdx.x;
  const int w = tid >> 6, lane = tid & 63, l15 = lane & 15, quad = lane >> 4;
  const short* wqh = WqT + (size_t)h * (HD * EMB);  // [d][e]
  f32x4 acc[4] = {};
  bf16x8 ar[2], br[2];
  load64(Xb, EMB, m0, 0, ar, tid);
  load64(wqh, EMB, 0, 0, br, tid);
  write64(As[0], ar, tid);
  write64(Bs[0], br, tid);
  load64(Xb, EMB, m0, 64, ar, tid);
  load64(wqh, EMB, 0, 64, br, tid);
  BAR();
  for (int k0 = 0; k0 < EMB; k0 += 64) {
    const int cur = (k0 >> 6) & 1;
    const short* Ac = As[cur];
    const short* Bc = Bs[cur];
    GEMM_TILE_COMPUTE(Ac, Bc, acc);
    if (k0 + 64 < EMB) {
      write64((short*)As[cur ^ 1], ar, tid);
      write64((short*)Bs[cur ^ 1], br, tid);
      if (k0 + 128 < EMB) {
        load64(Xb, EMB, m0, k0 + 128, ar, tid);
        load64(wqh, EMB, 0, k0 + 128, br, tid);
      }
    }
    BAR();
  }
  // stage result tile into As[0] as [tok][d]
  short* T = (short*)As[0];
#pragma unroll
  for (int nt = 0; nt < 4; ++nt)
#pragma unroll
    for (int r = 0; r < 4; ++r)
      T[SW64((w << 4) + (quad << 2) + r, (nt << 4) + l15)] = f2bf(acc[nt][r]);
  __syncthreads();
  {  // Qo[h][tok][d], coalesced b128 stores
    int r2 = tid >> 2, kb = (tid & 3) << 4;
    int g = kb >> 3;
    bf16x8 q0v = *(const bf16x8*)&T[r2 * 64 + ((g ^ (r2 & 7)) << 3)];
    bf16x8 q1v = *(const bf16x8*)&T[r2 * 64 + (((g + 1) ^ (r2 & 7)) << 3)];
    short* qo = Qo + (size_t)h * (BS_TOK * HD) + (size_t)(m0 + r2) * HD + kb;
    *(bf16x8*)(qo) = q0v;
    *(bf16x8*)(qo + 8) = q1v;
  }
  {  // Qt[h][d][tok], coalesced b128 stores
    int d = tid >> 2, tok0 = (tid & 3) << 4;
    bf16x8 t0, t1;
#pragma unroll
    for (int j = 0; j < 8; ++j) t0[j] = T[SW64(tok0 + j, d)];
#pragma unroll
    for (int j = 0; j < 8; ++j) t1[j] = T[SW64(tok0 + 8 + j, d)];
    short* qt = Qt + (size_t)h * (HD * BS_TOK) + (size_t)d * BS_TOK + m0 + tok0;
    *(bf16x8*)(qt) = t0;
    *(bf16x8*)(qt + 8) = t1;
  }
}

// ------------------------------------------------- flash attention
// 256 thr (4 waves), Q-tile 128 (2x16 rows/wave), K-tile 64, ksplit=4
// -> grid 16x12x4 = 768 blocks = 3/CU balanced. K/V LDS double-buffered,
// ONE LDS-only barrier per tile. S^T operand swap (qrow=l15).
__global__ __launch_bounds__(256, 3) void attn_mfma_kernel(const short* __restrict__ Q,
                                                           const short* __restrict__ Qt,
                                                           float* __restrict__ Opart,
                                                           float* __restrict__ Lpart) {
  __shared__ short Ks[2][64 * 64];   // K[key][d]
  __shared__ short Vt[2][64 * 64];   // V^T[d][key]
  __shared__ short Pw[4][32 * 64];   // per-wave P[qrow(32)][key(64)]
  const int h = blockIdx.y;
  const int q0 = blockIdx.x * 128;
  const int kt0 = blockIdx.z * 8;    // 8 K-tiles per split
  const int tid = threadIdx.x;
  const int lane = tid & 63;
  const int wv = tid >> 6;
  const int l15 = lane & 15;
  const int quad = lane >> 4;
  const short* Qh = Q + (size_t)h * (BS_TOK * HD);
  const short* Qth = Qt + (size_t)h * (HD * BS_TOK);
  short* myP = Pw[wv];

  bf16x8 qf[2][2];
#pragma unroll
  for (int sub = 0; sub < 2; ++sub) {
    const short* qp = Qh + (size_t)(q0 + wv * 32 + sub * 16 + l15) * HD + quad * 8;
    qf[sub][0] = *(const bf16x8*)(qp);
    qf[sub][1] = *(const bf16x8*)(qp + 32);
  }

  f32x4 o[2][4] = {};
  float lpl[2] = {0.f, 0.f};

  bf16x8 kreg[2], vreg[2];
#pragma unroll
  for (int i = 0; i < 2; ++i) {  // tile kt0
    int c = i * 256 + tid;
    kreg[i] = *(const bf16x8*)(Qh + (size_t)kt0 * 4096 + c * 8);
    vreg[i] = *(const bf16x8*)(Qth + (size_t)(c >> 3) * BS_TOK + kt0 * 64 + (c & 7) * 8);
  }
#pragma unroll
  for (int i = 0; i < 2; ++i) {  // -> buf 0
    int c = i * 256 + tid, row = c >> 3, g = c & 7;
    *(bf16x8*)&Ks[0][row * 64 + ((g ^ (row & 7)) << 3)] = kreg[i];
    *(bf16x8*)&Vt[0][row * 64 + ((g ^ (row & 7)) << 3)] = vreg[i];
  }
#pragma unroll
  for (int i = 0; i < 2; ++i) {  // tile kt0+1 in flight
    int c = i * 256 + tid;
    kreg[i] = *(const bf16x8*)(Qh + (size_t)(kt0 + 1) * 4096 + c * 8);
    vreg[i] = *(const bf16x8*)(Qth + (size_t)(c >> 3) * BS_TOK + (kt0 + 1) * 64 + (c & 7) * 8);
  }
  BAR();

  for (int kt = 0; kt < 8; ++kt) {
    const short* K_ = Ks[kt & 1];
    const short* V_ = Vt[kt & 1];

    // S^T = K Q^T ; lane: qrow = sub*16+l15, key = ct*16+quad*4+r
    f32x4 s[2][4];
    __builtin_amdgcn_s_setprio(1);
#pragma unroll
    for (int ct = 0; ct < 4; ++ct) {
      int row = ct * 16 + l15;
      bf16x8 kf0 = *(const bf16x8*)(&K_[row * 64 + ((quad ^ (row & 7)) << 3)]);
      bf16x8 kf1 = *(const bf16x8*)(&K_[row * 64 + (((4 + quad) ^ (row & 7)) << 3)]);
#pragma unroll
      for (int sub = 0; sub < 2; ++sub) {
        f32x4 a = (f32x4){0.f, 0.f, 0.f, 0.f};
        a = MFMA16(kf0, qf[sub][0], a);
        a = MFMA16(kf1, qf[sub][1], a);
        s[sub][ct] = a;
      }
    }
    __builtin_amdgcn_s_setprio(0);

    // no-max softmax: p = exp(s/8) = exp2(s*0.125*log2e); b64 P writes
#pragma unroll
    for (int sub = 0; sub < 2; ++sub) {
      int prow = sub * 16 + l15;
#pragma unroll
      for (int ct = 0; ct < 4; ++ct) {
        bf16x4 pv4;
#pragma unroll
        for (int r = 0; r < 4; ++r) {
          float p = exp2f(s[sub][ct][r] * 0.18033688011112042f);
          lpl[sub] += p;
          pv4[r] = f2bf(p);
        }
        int g = 2 * ct + (quad >> 1);
        *(bf16x4*)&myP[prow * 64 + ((g ^ (prow & 7)) << 3) + ((quad & 1) << 2)] = pv4;
      }
    }

    // O += P V  (wave-local myP; in-wave lgkmcnt ordering, no barrier)
    __builtin_amdgcn_s_setprio(1);
#pragma unroll
    for (int ks = 0; ks < 2; ++ks) {
      int c = ks * 4 + quad;
      bf16x8 pf0 = *(const bf16x8*)(&myP[l15 * 64 + ((c ^ (l15 & 7)) << 3)]);
      bf16x8 pf1 = *(const bf16x8*)(&myP[(16 + l15) * 64 + ((c ^ (l15 & 7)) << 3)]);
#pragma unroll
      for (int dt = 0; dt < 4; ++dt) {
        int row = dt * 16 + l15;
        bf16x8 vf = *(const bf16x8*)(&V_[row * 64 + ((c ^ (row & 7)) << 3)]);
        o[0][dt] = MFMA16(pf0, vf, o[0][dt]);
        o[1][dt] = MFMA16(pf1, vf, o[1][dt]);
      }
    }
    __builtin_amdgcn_s_setprio(0);

    if (kt + 1 < 8) {  // publish next tile into the other buffer
      short* Kn = (short*)Ks[(kt & 1) ^ 1];
      short* Vn = (short*)Vt[(kt & 1) ^ 1];
#pragma unroll
      for (int i = 0; i < 2; ++i) {
        int c = i * 256 + tid, row = c >> 3, g = c & 7;
        *(bf16x8*)&Kn[row * 64 + ((g ^ (row & 7)) << 3)] = kreg[i];
        *(bf16x8*)&Vn[row * 64 + ((g ^ (row & 7)) << 3)] = vreg[i];
      }
      if (kt + 2 < 8) {
        int gt = kt0 + kt + 2;
#pragma unroll
        for (int i = 0; i < 2; ++i) {
          int c = i * 256 + tid;
          kreg[i] = *(const bf16x8*)(Qh + (size_t)gt * 4096 + c * 8);
          vreg[i] = *(const bf16x8*)(Qth + (size_t)(c >> 3) * BS_TOK + gt * 64 + (c & 7) * 8);
        }
      }
    }
    BAR();
  }

  // reduce denominators across quads
#pragma unroll
  for (int sub = 0; sub < 2; ++sub) {
    lpl[sub] += __shfl_xor(lpl[sub], 16, 64);
    lpl[sub] += __shfl_xor(lpl[sub], 32, 64);
  }

  const int NB = BS_TOK * EMB;
  float* Oh = Opart + (size_t)blockIdx.z * NB + (size_t)h * (BS_TOK * HD);
  float* Lh = Lpart + ((size_t)blockIdx.z * NH + h) * BS_TOK;
  if (quad == 0) {
    Lh[q0 + wv * 32 + l15] = lpl[0];
    Lh[q0 + wv * 32 + 16 + l15] = lpl[1];
  }
#pragma unroll
  for (int sub = 0; sub < 2; ++sub)
#pragma unroll
    for (int r = 0; r < 4; ++r) {
      int qrow = q0 + wv * 32 + sub * 16 + quad * 4 + r;
#pragma unroll
      for (int dt = 0; dt < 4; ++dt)
        Oh[(size_t)qrow * HD + dt * 16 + l15] = o[sub][dt][r];
    }
}

// ------------------------------------------------- MH = Wo * combine(Opart)/l
// 128x64 tiles, ksplit=2; 4-way combine fused into B staging. Double-buffered.
__global__ __launch_bounds__(256) void gemm_out_kernel(const short* __restrict__ Wob,
                                                       const float* __restrict__ Op,
                                                       const float* __restrict__ Lp,
                                                       float* __restrict__ Pp) {
  __shared__ short As[2][128 * 64];
  __shared__ short Bs[2][64 * 64];
  const int n0 = blockIdx.x * 64;   // j cols (2048 -> 32)
  const int m0 = blockIdx.y * 128;  // e rows (768 -> 6)
  const int kz = blockIdx.z * 384;  // K half
  const int tid = threadIdx.x;
  const int w = tid >> 6, lane = tid & 63, l15 = lane & 15, quad = lane >> 4;
  f32x4 acc[2][4] = {};
  bf16x8 ar[4];
  float4 ca[4][4];
  float rl;
  load128(Wob, EMB, m0, kz, ar, tid);
  load_comb(Op, Lp, kz, n0, ca, rl, tid);
  write128((short*)As[0], ar, tid);
  write_comb((short*)Bs[0], ca, rl, tid);
  load128(Wob, EMB, m0, kz + 64, ar, tid);
  load_comb(Op, Lp, kz + 64, n0, ca, rl, tid);
  BAR();
  for (int k0 = 0; k0 < 384; k0 += 64) {
    const int cur = (k0 >> 6) & 1;
    const short* Ac = As[cur];
    const short* Bc = Bs[cur];
    GEMM_TILE_COMPUTE2(Ac, Bc, acc);
    if (k0 + 64 < 384) {
      write128((short*)As[cur ^ 1], ar, tid);
      write_comb((short*)Bs[cur ^ 1], ca, rl, tid);
      if (k0 + 128 < 384) {
        load128(Wob, EMB, m0, kz + k0 + 128, ar, tid);
        load_comb(Op, Lp, kz + k0 + 128, n0, ca, rl, tid);
      }
    }
    BAR();
  }
  float* P = Pp + (size_t)blockIdx.z * (BS_TOK * EMB);
#pragma unroll
  for (int u = 0; u < 2; ++u)
#pragma unroll
    for (int nt = 0; nt < 4; ++nt)
#pragma unroll
      for (int r = 0; r < 4; ++r)
        P[(size_t)(m0 + (w << 5) + (u << 4) + (quad << 2) + r) * BS_TOK + n0 +
          (nt << 4) + l15] = acc[u][nt][r];
}

// ------------------------------------------------- FFN = L1b * fwb^T + fb, 128x64, ksplit=2
__global__ __launch_bounds__(256) void gemm_ffn_kernel(const short* __restrict__ L1b,
                                                       const short* __restrict__ Fwb,
                                                       const float* __restrict__ Fb,
                                                       float* __restrict__ Pp) {
  __shared__ short As[2][128 * 64];
  __shared__ short Bs[2][64 * 64];
  const int m0 = blockIdx.x * 128;  // token tile (16)
  const int n0 = blockIdx.y * 64;   // out-feature tile (12)
  const int kz = blockIdx.z * 384;  // K half
  const int tid = threadIdx.x;
  const int w = tid >> 6, lane = tid & 63, l15 = lane & 15, quad = lane >> 4;
  f32x4 acc[2][4] = {};
  bf16x8 ar[4], br[2];
  load128(L1b, EMB, m0, kz, ar, tid);
  load64(Fwb, EMB, n0, kz, br, tid);
  write128((short*)As[0], ar, tid);
  write64((short*)Bs[0], br, tid);
  load128(L1b, EMB, m0, kz + 64, ar, tid);
  load64(Fwb, EMB, n0, kz + 64, br, tid);
  BAR();
  for (int k0 = 0; k0 < 384; k0 += 64) {
    const int cur = (k0 >> 6) & 1;
    const short* Ac = As[cur];
    const short* Bc = Bs[cur];
    GEMM_TILE_COMPUTE2(Ac, Bc, acc);
    if (k0 + 64 < 384) {
      write128((short*)As[cur ^ 1], ar, tid);
      write64((short*)Bs[cur ^ 1], br, tid);
      if (k0 + 128 < 384) {
        load128(L1b, EMB, m0, kz + k0 + 128, ar, tid);
        load64(Fwb, EMB, n0, kz + k0 + 128, br, tid);
      }
    }
    BAR();
  }
  float* P = Pp + (size_t)blockIdx.z * (BS_TOK * EMB);
  const bool addb = (blockIdx.z == 0);
#pragma unroll
  for (int nt = 0; nt < 4; ++nt) {
    float bias = addb ? Fb[n0 + (nt << 4) + l15] : 0.0f;
#pragma unroll
    for (int u = 0; u < 2; ++u)
#pragma unroll
      for (int r = 0; r < 4; ++r)
        P[(size_t)(m0 + (w << 5) + (u << 4) + (quad << 2) + r) * EMB + n0 +
          (nt << 4) + l15] = acc[u][nt][r] + bias;
  }
}

// ------------------------------------------------- LN(Xa + P0 + P1) -> fp32 + bf16
// Wave-per-token: 4 tokens/block, shuffle-only reductions, no LDS/barriers.
__global__ __launch_bounds__(256) void ln_kernel(const float* __restrict__ Xa,
                                                 const float* __restrict__ P,
                                                 const float* __restrict__ g,
                                                 const float* __restrict__ bb,
                                                 float* __restrict__ Out,
                                                 short* __restrict__ Outb) {
  const int NB = BS_TOK * EMB;
  const int wv = threadIdx.x >> 6, lane = threadIdx.x & 63;
  const int t = blockIdx.x * 4 + wv;
  const float* xa = Xa + (size_t)t * EMB;
  const float* p0 = P + (size_t)t * EMB;
  const float* p1 = p0 + NB;
  float4 v[3];
  float s = 0.f;
#pragma unroll
  for (int i = 0; i < 3; ++i) {
    int e = lane * 4 + i * 256;
    float4 a = *(const float4*)(xa + e);
    float4 b = *(const float4*)(p0 + e);
    float4 c = *(const float4*)(p1 + e);
    v[i].x = a.x + b.x + c.x;
    v[i].y = a.y + b.y + c.y;
    v[i].z = a.z + b.z + c.z;
    v[i].w = a.w + b.w + c.w;
    s += v[i].x + v[i].y + v[i].z + v[i].w;
  }
#pragma unroll
  for (int o = 32; o > 0; o >>= 1) s += __shfl_xor(s, o, 64);
  float mu = s * (1.0f / EMB);
  float q = 0.f;
#pragma unroll
  for (int i = 0; i < 3; ++i) {
    float dx = v[i].x - mu, dy = v[i].y - mu, dz = v[i].z - mu, dw = v[i].w - mu;
    q += dx * dx + dy * dy + dz * dz + dw * dw;
  }
#pragma unroll
  for (int o = 32; o > 0; o >>= 1) q += __shfl_xor(q, o, 64);
  float var = q * (1.0f / EMB);
  float r = rsqrtf(var + 1e-5f);
#pragma unroll
  for (int i = 0; i < 3; ++i) {
    int e = lane * 4 + i * 256;
    float4 gg = *(const float4*)(g + e);
    float4 bv = *(const float4*)(bb + e);
    float4 res;
    res.x = (v[i].x - mu) * r * gg.x + bv.x;
    res.y = (v[i].y - mu) * r * gg.y + bv.y;
    res.z = (v[i].z - mu) * r * gg.z + bv.z;
    res.w = (v[i].w - mu) * r * gg.w + bv.w;
    *(float4*)(Out + (size_t)t * EMB + e) = res;
    bf16x4 ob;
    ob[0] = f2bf(res.x);
    ob[1] = f2bf(res.y);
    ob[2] = f2bf(res.z);
    ob[3] = f2bf(res.w);
    *(bf16x4*)(Outb + (size_t)t * EMB + e) = ob;
  }
}

extern "C" void kernel_launch(void* const* d_in, const int* in_sizes, int n_in,
                              void* d_out, int out_size, void* d_ws, size_t ws_size,
                              hipStream_t stream) {
  const float* tok = (const float*)d_in[0];
  const float* wq = (const float*)d_in[1];
  const float* wo = (const float*)d_in[2];
  const float* g1 = (const float*)d_in[3];
  const float* b1 = (const float*)d_in[4];
  const float* fw = (const float*)d_in[5];
  const float* fb = (const float*)d_in[6];
  const float* g2 = (const float*)d_in[7];
  const float* b2 = (const float*)d_in[8];
  const int NB = BS_TOK * EMB;  // 1572864 elems
  float* bufA = (float*)d_ws;         // X (residual, fp32)
  float* bufB = bufA + NB;            // gemm partial 0
  float* bufC = bufB + NB;            // gemm partial 1
  float* bufD = bufC + NB;            // L1 fp32
  float* opart = bufD + NB;           // attn O partials [4][NB]
  short* XbA = (short*)(opart + 4 * (size_t)NB);  // bf16 of current X
  short* L1b = XbA + NB;              // bf16 of L1
  short* Qbf = L1b + NB;              // Q bf16 [H][2048][64]
  short* Qtb = Qbf + NB;              // Qt bf16 [H][64][2048]
  short* wqTb = Qtb + NB;             // wqT bf16 [L][H][64][768]
  short* wob = wqTb + WQN;            // wo bf16 [L][768][768]
  short* fwb = wob + WQN;             // fw bf16 [L][768][768]
  float* Lpart = (float*)(fwb + WQN); // [4][H][2048]

  cvt_weights_kernel<<<dim3(WQN / (256 * 8), 2), 256, 0, stream>>>(wo, fw, wob, fwb);
  wq_trans_kernel<<<dim3(12, 12 * NH), 256, 0, stream>>>(wq, wqTb);
  pe_add_kernel<<<NB / 256, 256, 0, stream>>>(tok, bufA, XbA);
  for (int it = 0; it < 13; ++it) {
    int l = (it == 0) ? 0 : it - 1;  // layer 0 applied twice (faithful)
    gemm_q_kernel<<<dim3(32, NH), 256, 0, stream>>>(
        XbA, wqTb + (size_t)l * (NH * HD * EMB), Qbf, Qtb);
    attn_mfma_kernel<<<dim3(16, NH, 4), 256, 0, stream>>>(Qbf, Qtb, opart, Lpart);
    gemm_out_kernel<<<dim3(32, 6, 2), 256, 0, stream>>>(
        wob + (size_t)l * (EMB * EMB), opart, Lpart, bufB);
    ln_kernel<<<BS_TOK / 4, 256, 0, stream>>>(bufA, bufB, g1 + l * EMB, b1 + l * EMB,
                                              bufD, L1b);
    gemm_ffn_kernel<<<dim3(16, 12, 2), 256, 0, stream>>>(
        L1b, fwb + (size_t)l * (EMB * EMB), fb + l * EMB, bufB);
    float* ln2_dst = (it == 12) ? (float*)d_out : bufA;
    ln_kernel<<<BS_TOK / 4, 256, 0, stream>>>(bufD, bufB, g2 + l * EMB, b2 + l * EMB,
                                              ln2_dst, XbA);
  }
}